// Round 1
// baseline (2255.534 us; speedup 1.0000x reference)
//
#include <hip/hip_runtime.h>
#include <hip/hip_bf16.h>

// Problem constants
constexpr int NB  = 16;     // batch
constexpr int DIN = 512;    // channels
constexpr int TT  = 4096;   // time
constexpr int NCB = 9;      // codebooks
constexpr int KK  = 1024;   // entries per codebook

// output layout (FLOAT32: codes, latent, closs, bloss)
constexpr size_t OUT_LAT   = (size_t)NB * NCB * TT;            // 589824
constexpr size_t OUT_CLOSS = OUT_LAT + (size_t)NB * DIN * TT;  // 34144256

// LDS stride for residual rows: 516 keeps 16B alignment for float4 reads
// (516*4 = 2064 = 129*16) and bank stride 4 -> 2-way conflict (free, m136).
constexpr int SRES = 516;

// Scratch as __device__ globals (round-0 postmortem: never trust ws_size).
// NOTE round-5 relayouts: cbn/c2/wout/obt are stored TRANSPOSED so each
// thread's k- (or c-) walk is sequential:  k -> [i][k&15][k>>4]
__device__ __align__(16) float g_cbn [NCB * KK * 8];   // [i][grp16][j64][8]
__device__ __align__(16) float g_c2  [NCB * KK];       // [i][grp16][j64]
__device__ __align__(16) float g_win [NCB * 8 * DIN];  // [i][o][c] (unchanged)
__device__ __align__(16) float g_wout[NCB * DIN * 8];  // [i][grp16][j32][8]
__device__ __align__(16) float g_obt [NCB * DIN];      // [i][grp16][j32]
__device__ double g_loss;

// square with forced separate rounding (blocks -ffp-contract=fast fusing the
// mul into a following add — numpy rounds every square before summing)
__device__ __forceinline__ float sqf(float x) {
  float r = x * x;
  asm volatile("" : "+v"(r));
  return r;
}

// ---------- prep: weight-norm for in_proj ----------
// EXACT numpy pairwise_sum(n=512) mirror for ||v|| (unchanged from round 4).
__global__ void prep_win_k(const float* __restrict__ in_v, const float* __restrict__ in_g) {
  const int r = blockIdx.x * 64 + threadIdx.x;  // i*8 + o, < 72
  if (r >= NCB * 8) return;
  const float* v = in_v + (size_t)r * DIN;
  float blk[4];
#pragma unroll
  for (int bb = 0; bb < 4; ++bb) {
    const float* a = v + bb * 128;
    float r8[8];
#pragma unroll
    for (int j = 0; j < 8; ++j) r8[j] = sqf(a[j]);
#pragma unroll
    for (int m = 1; m < 16; ++m)
#pragma unroll
      for (int j = 0; j < 8; ++j) r8[j] += sqf(a[m * 8 + j]);
    blk[bb] = ((r8[0] + r8[1]) + (r8[2] + r8[3])) + ((r8[4] + r8[5]) + (r8[6] + r8[7]));
  }
  const float total = (blk[0] + blk[1]) + (blk[2] + blk[3]);
  const float nrm = sqrtf(total);               // IEEE sqrt (HIP default precise)
  const float g = in_g[r];
  float* w = g_win + (size_t)r * DIN;
  for (int c = 0; c < DIN; ++c) w[c] = (g * v[c]) / nrm;  // np: (g*v) rounds, then /
}

// ---------- prep: weight-norm for out_proj (n=8 np tree) + transposed store ----------
__global__ void prep_wout_k(const float* __restrict__ out_v, const float* __restrict__ out_g,
                            const float* __restrict__ out_b) {
  const int row = blockIdx.x * 256 + threadIdx.x;  // i*512 + c, < 4608
  const float* v = out_v + (size_t)row * 8;
  float q[8];
#pragma unroll
  for (int d = 0; d < 8; ++d) q[d] = sqf(v[d]);
  const float nrm = sqrtf(((q[0] + q[1]) + (q[2] + q[3])) + ((q[4] + q[5]) + (q[6] + q[7])));
  const float g = out_g[row];
  const int i = row >> 9, c = row & 511;
  float* w = g_wout + (((size_t)i * 16 + (c & 15)) * 32 + (c >> 4)) * 8;
#pragma unroll
  for (int d = 0; d < 8; ++d) w[d] = (g * v[d]) / nrm;   // values identical, layout transposed
  g_obt[((size_t)i * 16 + (c & 15)) * 32 + (c >> 4)] = out_b[row];
}

// ---------- prep: normalized codebooks + squared norms (transposed); zero loss ----------
__global__ void prep_cbn_k(const float* __restrict__ cb) {
  const int row = blockIdx.x * 256 + threadIdx.x;  // i*1024 + k, < 9216
  const float* v = cb + (size_t)row * 8;
  float q[8];
#pragma unroll
  for (int d = 0; d < 8; ++d) q[d] = sqf(v[d]);
  float nrm = sqrtf(((q[0] + q[1]) + (q[2] + q[3])) + ((q[4] + q[5]) + (q[6] + q[7])));
  nrm = fmaxf(nrm, 1e-12f);
  const int i = row >> 10, k = row & 1023;
  float* dst = g_cbn + (((size_t)i * 16 + (k & 15)) * 64 + (k >> 4)) * 8;
  float cn[8];
#pragma unroll
  for (int d = 0; d < 8; ++d) { cn[d] = v[d] / nrm; dst[d] = cn[d]; }
  float s2[8];
#pragma unroll
  for (int d = 0; d < 8; ++d) s2[d] = sqf(cn[d]);
  g_c2[(size_t)i * 1024 + (k & 15) * 64 + (k >> 4)] =
      ((s2[0] + s2[1]) + (s2[2] + s2[3])) + ((s2[4] + s2[5]) + (s2[6] + s2[7]));
  if (row == 0) g_loss = 0.0;
}

// ---------- main fused RVQ chain ----------
// Round-5 restructure: no s_win (W_in read from global, L1-resident broadcast)
// -> LDS 34.7KB -> 4 blocks/CU; A1 uses float4 LDS reads; A2 merged into A1
// via in-wave shfl butterfly (bitwise == np pairwise tree by add commutativity);
// B-red collapsed to a shfl tree + 3 compares; STE/cb-row fetch moved into the
// all-thread D phase. 4 barriers/iter (was 5).
__global__ __launch_bounds__(256, 4)
void rvq_main_k(const float* __restrict__ z, const float* __restrict__ in_b,
                const float* __restrict__ cb, float* __restrict__ out) {
  __shared__ __align__(16) float s_res[16 * SRES];  // residual [col][c]
  __shared__ float s_ze[128];   // z_e [d][col]
  __shared__ float s_en[128];   // enc_n [d][col]
  __shared__ float s_s[16];     // sum(enc_n^2) per col
  __shared__ float s_cd[64];    // per-wave best dist [wave][col]
  __shared__ int   s_ck[64];    // per-wave best k
  __shared__ int   s_bk[16];    // final argmin k per col

  const int tid = threadIdx.x;
  const int col = tid & 15;
  const int grp = tid >> 4;
  const int b   = blockIdx.x >> 8;
  const int t0  = (blockIdx.x & 255) << 4;

  // init: residual = z in LDS; latent accumulator lr = 0 in registers.
  // (reference accumulates latent per step in f32 — mirror exactly)
  float lr[32];
  {
    const float* zb = z + (size_t)b * DIN * TT + t0 + col;
#pragma unroll
    for (int j = 0; j < 32; ++j) {
      const int c = grp + (j << 4);
      s_res[col * SRES + c] = zb[(size_t)c * TT];
      lr[j] = 0.0f;
    }
  }

  float loss_acc = 0.0f;

  for (int i = 0; i < NCB; ++i) {
    __syncthreads();  // orders prev-D s_res writes / s_ze reads vs A1 below

    // ---- A1+A2: in-proj + normalize (tid<128 = waves 0,1; col=tid>>3, o=tid&7
    // puts the 8 d's of a column in 8 adjacent lanes -> shfl-tree normalize).
    // numpy einsum SOP path: single sequential fmaf chain, c ascending —
    // float4 keeps the identical .x,.y,.z,.w order.
    if (tid < 128) {
      const int a_col = tid >> 3, a_o = tid & 7;
      const float4* wr = (const float4*)(g_win + ((size_t)i * 8 + a_o) * DIN);
      const float4* rr = (const float4*)(s_res + a_col * SRES);
      float acc = 0.0f;
#pragma unroll 8
      for (int h = 0; h < 128; ++h) {
        const float4 w = wr[h];
        const float4 r = rr[h];
        acc = fmaf(w.x, r.x, acc);
        acc = fmaf(w.y, r.y, acc);
        acc = fmaf(w.z, r.z, acc);
        acc = fmaf(w.w, r.w, acc);
      }
      const float ze = acc + in_b[i * 8 + a_o];  // bias added after (np.add)
      s_ze[a_o * 16 + a_col] = ze;
      // normalize: np pairwise-8 tree == 3-step shfl butterfly (IEEE add is
      // commutative, so every lane computes the bitwise-identical sum)
      const float q = sqf(ze);
      const float t1 = q + __shfl_xor(q, 1);
      const float t2 = t1 + __shfl_xor(t1, 2);
      const float t3 = t2 + __shfl_xor(t2, 4);
      float nrm = sqrtf(t3);
      nrm = fmaxf(nrm, 1e-12f);
      const float en = ze / nrm;                 // IEEE div per element (np)
      s_en[a_o * 16 + a_col] = en;
      const float s2 = sqf(en);
      const float u1 = s2 + __shfl_xor(s2, 1);
      const float u2 = u1 + __shfl_xor(u1, 2);
      const float u3 = u2 + __shfl_xor(u2, 4);
      if (a_o == 0) s_s[a_col] = u3;
    }
    __syncthreads();

    // ---- B: distance scan, k = 16j+grp per thread (transposed layout: walk
    // is sequential in memory, j ascending == k ascending within subset).
    // np: dist = (s - 2*dot) + c2; 2*dot exact, so fmaf(-2,dot,s) == s - dot2.
    {
      const float en0 = s_en[col],      en1 = s_en[16 + col];
      const float en2 = s_en[32 + col], en3 = s_en[48 + col];
      const float en4 = s_en[64 + col], en5 = s_en[80 + col];
      const float en6 = s_en[96 + col], en7 = s_en[112 + col];
      const float sv = s_s[col];
      const float* cp  = g_cbn + ((size_t)i * 16 + grp) * 512;
      const float* c2p = g_c2  + ((size_t)i * 16 + grp) * 64;
      float dmin = 3.402823466e38f; int jmin = 0;
      for (int jo = 0; jo < 16; ++jo) {
        const float4 c2q = *(const float4*)(c2p + jo * 4);
        const float c2a[4] = {c2q.x, c2q.y, c2q.z, c2q.w};
#pragma unroll
        for (int ji = 0; ji < 4; ++ji) {
          const int j = jo * 4 + ji;
          const float4 c0 = *(const float4*)(cp + j * 8);
          const float4 c1 = *(const float4*)(cp + j * 8 + 4);
          float dot = 0.0f;
          dot = fmaf(en0, c0.x, dot); dot = fmaf(en1, c0.y, dot);
          dot = fmaf(en2, c0.z, dot); dot = fmaf(en3, c0.w, dot);
          dot = fmaf(en4, c1.x, dot); dot = fmaf(en5, c1.y, dot);
          dot = fmaf(en6, c1.z, dot); dot = fmaf(en7, c1.w, dot);
          const float dist = fmaf(-2.0f, dot, sv) + c2a[ji];
          if (dist < dmin) { dmin = dist; jmin = j; }  // strict <, j asc = first-min
        }
      }
      int kmin = (jmin << 4) + grp;
      // in-wave argmin over the wave's 4 grp-subsets (min-with-lowest-k-tie is
      // associative; identical result to the old sequential 16-scan)
      float od = __shfl_xor(dmin, 16); int ok = __shfl_xor(kmin, 16);
      if (od < dmin || (od == dmin && ok < kmin)) { dmin = od; kmin = ok; }
      od = __shfl_xor(dmin, 32); ok = __shfl_xor(kmin, 32);
      if (od < dmin || (od == dmin && ok < kmin)) { dmin = od; kmin = ok; }
      if ((tid & 48) == 0) {
        s_cd[(tid >> 6) * 16 + col] = dmin;
        s_ck[(tid >> 6) * 16 + col] = kmin;
      }
    }
    __syncthreads();

    // ---- B-red: combine 4 per-wave candidates (np first-min tie rule), codes
    if (tid < 16) {
      float bd = s_cd[tid]; int bk = s_ck[tid];
#pragma unroll
      for (int w = 1; w < 4; ++w) {
        const float d2 = s_cd[w * 16 + tid]; const int k2 = s_ck[w * 16 + tid];
        if (d2 < bd || (d2 == bd && k2 < bk)) { bd = d2; bk = k2; }
      }
      out[((size_t)b * NCB + i) * TT + t0 + tid] = (float)bk;
      s_bk[tid] = bk;
    }
    __syncthreads();

    // ---- D: STE in-register (16-way broadcast cb-row load), out-proj
    // (einsum SOP: FMA ascending d) + latent & residual update
    {
      const int bk = s_bk[col];
      const float* cr = cb + ((size_t)i * KK + bk) * 8;  // RAW codebook row
      const float4 cq0 = *(const float4*)(cr);
      const float4 cq1 = *(const float4*)(cr + 4);
      const float zqa[8] = {cq0.x, cq0.y, cq0.z, cq0.w, cq1.x, cq1.y, cq1.z, cq1.w};
      float qst[8];
#pragma unroll
      for (int d = 0; d < 8; ++d) {
        const float ze = s_ze[d * 16 + col];
        const float zq = zqa[d];
        qst[d] = ze + (zq - ze);                 // STE rounding mirrored
        if (grp == 0) {                          // loss counted once per (d,col)
          const float df = ze - zq;
          loss_acc = fmaf(df, df, loss_acc);     // loss precision uncritical (2% thr)
        }
      }
      const float* gw  = g_wout + ((size_t)i * 16 + grp) * 256;  // 32 j x 8
      const float* obp = g_obt  + ((size_t)i * 16 + grp) * 32;
      for (int jo = 0; jo < 8; ++jo) {
        const float4 obq = *(const float4*)(obp + jo * 4);
        const float oba[4] = {obq.x, obq.y, obq.z, obq.w};
#pragma unroll
        for (int ji = 0; ji < 4; ++ji) {
          const int j = jo * 4 + ji;
          const float4 w0 = *(const float4*)(gw + j * 8);
          const float4 w1 = *(const float4*)(gw + j * 8 + 4);
          float dot = 0.0f;
          dot = fmaf(w0.x, qst[0], dot); dot = fmaf(w0.y, qst[1], dot);
          dot = fmaf(w0.z, qst[2], dot); dot = fmaf(w0.w, qst[3], dot);
          dot = fmaf(w1.x, qst[4], dot); dot = fmaf(w1.y, qst[5], dot);
          dot = fmaf(w1.z, qst[6], dot); dot = fmaf(w1.w, qst[7], dot);
          const float lat = dot + oba[ji];       // einsum + bias (one rounded add)
          lr[j] += lat;                          // latent += lat_i (np per-step f32)
          s_res[col * SRES + grp + (j << 4)] -= lat;  // residual -= lat_i
        }
      }
    }
    // no trailing barrier: loop-top barrier orders D vs next A1
  }

  // latent output (exact per-step accumulation)
  {
    float* lat = out + OUT_LAT;
#pragma unroll
    for (int j = 0; j < 32; ++j) {
      const int c = grp + (j << 4);
      lat[((size_t)b * DIN + c) * TT + t0 + col] = lr[j];
    }
  }

  // loss reduce (nonzero only lanes 0..15 of wave 0), one atomic per block
  if (tid < 64) {
    float v = loss_acc;
#pragma unroll
    for (int off = 32; off; off >>= 1) v += __shfl_down(v, off);
    if (tid == 0) atomicAdd(&g_loss, (double)v);
  }
}

// ---------- epilogue: finalize scalar losses ----------
__global__ void rvq_epi_k(float* __restrict__ out) {
  const float m = (float)(g_loss / 524288.0);  // B*D_CB*T
  out[OUT_CLOSS]     = m;
  out[OUT_CLOSS + 1] = m;
}

extern "C" void kernel_launch(void* const* d_in, const int* in_sizes, int n_in,
                              void* d_out, int out_size, void* d_ws, size_t ws_size,
                              hipStream_t stream) {
  const float* z     = (const float*)d_in[0];
  const float* in_v  = (const float*)d_in[1];
  const float* in_g  = (const float*)d_in[2];
  const float* in_b  = (const float*)d_in[3];
  const float* out_v = (const float*)d_in[4];
  const float* out_g = (const float*)d_in[5];
  const float* out_b = (const float*)d_in[6];
  const float* cb    = (const float*)d_in[7];
  float* out = (float*)d_out;
  (void)d_ws; (void)ws_size;

  prep_win_k <<<2, 64, 0, stream>>>(in_v, in_g);
  prep_wout_k<<<18, 256, 0, stream>>>(out_v, out_g, out_b);
  prep_cbn_k <<<36, 256, 0, stream>>>(cb);
  rvq_main_k <<<4096, 256, 0, stream>>>(z, in_b, cb, out);
  rvq_epi_k  <<<1, 1, 0, stream>>>(out);
}

// Round 2
// 1403.957 us; speedup vs baseline: 1.6066x; 1.6066x over previous
//
#include <hip/hip_runtime.h>
#include <hip/hip_bf16.h>

// Problem constants
constexpr int NB  = 16;     // batch
constexpr int DIN = 512;    // channels
constexpr int TT  = 4096;   // time
constexpr int NCB = 9;      // codebooks
constexpr int KK  = 1024;   // entries per codebook

// output layout (FLOAT32: codes, latent, closs, bloss)
constexpr size_t OUT_LAT   = (size_t)NB * NCB * TT;            // 589824
constexpr size_t OUT_CLOSS = OUT_LAT + (size_t)NB * DIN * TT;  // 34144256

// LDS strides — bank math is per 32-lane phase (SIMD-32):
// SRES = 514 (≡2 mod 32): D-phase RMW at col*S+grp maps 2c+g onto all 32
//   banks exactly once per phase (round-0 measured ZERO conflicts).
//   float2-aligned (514*4 % 8 == 0) — A1 reads float2, NOT float4.
// SWIN = 516: float4-aligned for the staging writes; A1 reads float2.
constexpr int SRES = 514;
constexpr int SWIN = 516;

// Scratch as __device__ globals (round-0 postmortem: never trust ws_size).
// cbn/c2/wout/obt stored TRANSPOSED (k -> [i][k&15][k>>4]) so each thread's
// k-walk in B / c-walk in D is a sequential stream (round-1 verified).
__device__ __align__(16) float g_cbn [NCB * KK * 8];   // [i][grp16][j64][8]
__device__ __align__(16) float g_c2  [NCB * KK];       // [i][grp16][j64]
__device__ __align__(16) float g_win [NCB * 8 * DIN];  // [i][o][c]
__device__ __align__(16) float g_wout[NCB * DIN * 8];  // [i][grp16][j32][8]
__device__ __align__(16) float g_obt [NCB * DIN];      // [i][grp16][j32]
__device__ double g_loss;

// square with forced separate rounding (blocks -ffp-contract=fast fusing the
// mul into a following add — numpy rounds every square before summing)
__device__ __forceinline__ float sqf(float x) {
  float r = x * x;
  asm volatile("" : "+v"(r));
  return r;
}

// ---------- prep: weight-norm for in_proj ----------
// EXACT numpy pairwise_sum(n=512) mirror for ||v||.
__global__ void prep_win_k(const float* __restrict__ in_v, const float* __restrict__ in_g) {
  const int r = blockIdx.x * 64 + threadIdx.x;  // i*8 + o, < 72
  if (r >= NCB * 8) return;
  const float* v = in_v + (size_t)r * DIN;
  float blk[4];
#pragma unroll
  for (int bb = 0; bb < 4; ++bb) {
    const float* a = v + bb * 128;
    float r8[8];
#pragma unroll
    for (int j = 0; j < 8; ++j) r8[j] = sqf(a[j]);
#pragma unroll
    for (int m = 1; m < 16; ++m)
#pragma unroll
      for (int j = 0; j < 8; ++j) r8[j] += sqf(a[m * 8 + j]);
    blk[bb] = ((r8[0] + r8[1]) + (r8[2] + r8[3])) + ((r8[4] + r8[5]) + (r8[6] + r8[7]));
  }
  const float total = (blk[0] + blk[1]) + (blk[2] + blk[3]);
  const float nrm = sqrtf(total);               // IEEE sqrt (HIP default precise)
  const float g = in_g[r];
  float* w = g_win + (size_t)r * DIN;
  for (int c = 0; c < DIN; ++c) w[c] = (g * v[c]) / nrm;  // np: (g*v) rounds, then /
}

// ---------- prep: weight-norm for out_proj (n=8 np tree) + transposed store ----------
__global__ void prep_wout_k(const float* __restrict__ out_v, const float* __restrict__ out_g,
                            const float* __restrict__ out_b) {
  const int row = blockIdx.x * 256 + threadIdx.x;  // i*512 + c, < 4608
  const float* v = out_v + (size_t)row * 8;
  float q[8];
#pragma unroll
  for (int d = 0; d < 8; ++d) q[d] = sqf(v[d]);
  const float nrm = sqrtf(((q[0] + q[1]) + (q[2] + q[3])) + ((q[4] + q[5]) + (q[6] + q[7])));
  const float g = out_g[row];
  const int i = row >> 9, c = row & 511;
  float* w = g_wout + (((size_t)i * 16 + (c & 15)) * 32 + (c >> 4)) * 8;
#pragma unroll
  for (int d = 0; d < 8; ++d) w[d] = (g * v[d]) / nrm;   // values identical, layout transposed
  g_obt[((size_t)i * 16 + (c & 15)) * 32 + (c >> 4)] = out_b[row];
}

// ---------- prep: normalized codebooks + squared norms (transposed); zero loss ----------
__global__ void prep_cbn_k(const float* __restrict__ cb) {
  const int row = blockIdx.x * 256 + threadIdx.x;  // i*1024 + k, < 9216
  const float* v = cb + (size_t)row * 8;
  float q[8];
#pragma unroll
  for (int d = 0; d < 8; ++d) q[d] = sqf(v[d]);
  float nrm = sqrtf(((q[0] + q[1]) + (q[2] + q[3])) + ((q[4] + q[5]) + (q[6] + q[7])));
  nrm = fmaxf(nrm, 1e-12f);
  const int i = row >> 10, k = row & 1023;
  float* dst = g_cbn + (((size_t)i * 16 + (k & 15)) * 64 + (k >> 4)) * 8;
  float cn[8];
#pragma unroll
  for (int d = 0; d < 8; ++d) { cn[d] = v[d] / nrm; dst[d] = cn[d]; }
  float s2[8];
#pragma unroll
  for (int d = 0; d < 8; ++d) s2[d] = sqf(cn[d]);
  g_c2[(size_t)i * 1024 + (k & 15) * 64 + (k >> 4)] =
      ((s2[0] + s2[1]) + (s2[2] + s2[3])) + ((s2[4] + s2[5]) + (s2[6] + s2[7]));
  if (row == 0) g_loss = 0.0;
}

// ---------- main fused RVQ chain ----------
// Round-2 structure: W_in staged in LDS (round-0, conflict-free, measured);
// A1 float2 chain with merged shfl normalize (round-1 verified); B on
// transposed streams with in-wave argmin; B-red folded into D (all lanes
// redundantly reduce 4 candidates — associative, identical result).
// 3 barriers/iter (round 0 had 5).
__global__ __launch_bounds__(256, 3)
void rvq_main_k(const float* __restrict__ z, const float* __restrict__ in_b,
                const float* __restrict__ cb, float* __restrict__ out) {
  __shared__ __align__(16) float s_res[16 * SRES];  // residual [col][c]
  __shared__ __align__(16) float s_win[8 * SWIN];   // W_in rows [o][c]
  __shared__ float s_ze[128];   // z_e [d][col]
  __shared__ float s_en[128];   // enc_n [d][col]
  __shared__ float s_s[16];     // sum(enc_n^2) per col
  __shared__ float s_cd[64];    // per-wave best dist [wave][col]
  __shared__ int   s_ck[64];    // per-wave best k

  const int tid = threadIdx.x;
  const int col = tid & 15;
  const int grp = tid >> 4;
  const int b   = blockIdx.x >> 8;
  const int t0  = (blockIdx.x & 255) << 4;

  // init: residual = z in LDS; latent accumulator lr = 0 in registers.
  float lr[32];
  {
    const float* zb = z + (size_t)b * DIN * TT + t0 + col;
#pragma unroll
    for (int j = 0; j < 32; ++j) {
      const int c = grp + (j << 4);
      s_res[col * SRES + c] = zb[(size_t)c * TT];
      lr[j] = 0.0f;
    }
  }

  float loss_acc = 0.0f;

  for (int i = 0; i < NCB; ++i) {
    // ---- stage W_in into LDS (padded rows; disjoint from D's footprint,
    // so it overlaps the tail of the previous iteration's D across threads)
    {
      const float4* gw = (const float4*)(g_win + i * 4096);
#pragma unroll
      for (int q = 0; q < 4; ++q) {
        const int e = (q * 256 + tid) * 4;
        *(float4*)(s_win + (e >> 9) * SWIN + (e & 511)) = gw[q * 256 + tid];
      }
    }
    __syncthreads();  // orders: stage writes + prev-D s_res writes vs A1 reads

    // ---- A1+A2: in-proj + normalize. tid<128; col=tid>>3, o=tid&7 puts the
    // 8 d's of a column in 8 adjacent lanes -> shfl-tree normalize (bitwise ==
    // np pairwise-8 tree by IEEE add commutativity; round-1 verified).
    // einsum SOP path: single sequential fmaf chain, c ascending (float2).
    if (tid < 128) {
      const int a_col = tid >> 3, a_o = tid & 7;
      const float2* wr = (const float2*)(s_win + a_o * SWIN);
      const float2* rr = (const float2*)(s_res + a_col * SRES);
      float acc = 0.0f;
#pragma unroll 8
      for (int h = 0; h < 256; ++h) {
        const float2 w = wr[h];
        const float2 r = rr[h];
        acc = fmaf(w.x, r.x, acc);
        acc = fmaf(w.y, r.y, acc);
      }
      const float ze = acc + in_b[i * 8 + a_o];  // bias added after (np.add)
      s_ze[a_o * 16 + a_col] = ze;
      const float q = sqf(ze);
      const float t1 = q + __shfl_xor(q, 1);
      const float t2 = t1 + __shfl_xor(t1, 2);
      const float t3 = t2 + __shfl_xor(t2, 4);
      float nrm = sqrtf(t3);
      nrm = fmaxf(nrm, 1e-12f);
      const float en = ze / nrm;                 // IEEE div per element (np)
      s_en[a_o * 16 + a_col] = en;
      const float s2 = sqf(en);
      const float u1 = s2 + __shfl_xor(s2, 1);
      const float u2 = u1 + __shfl_xor(u1, 2);
      const float u3 = u2 + __shfl_xor(u2, 4);
      if (a_o == 0) s_s[a_col] = u3;
    }
    __syncthreads();

    // ---- B: distance scan, k = 16j+grp per thread; transposed layout makes
    // the walk a sequential 2KB stream per lane-group (16-lane broadcast).
    // np: dist = (s - 2*dot) + c2; 2*dot exact, so fmaf(-2,dot,s) == s - dot2.
    {
      const float en0 = s_en[col],      en1 = s_en[16 + col];
      const float en2 = s_en[32 + col], en3 = s_en[48 + col];
      const float en4 = s_en[64 + col], en5 = s_en[80 + col];
      const float en6 = s_en[96 + col], en7 = s_en[112 + col];
      const float sv = s_s[col];
      const float* cp  = g_cbn + ((size_t)i * 16 + grp) * 512;
      const float* c2p = g_c2  + ((size_t)i * 16 + grp) * 64;
      float dmin = 3.402823466e38f; int jmin = 0;
#pragma unroll 2
      for (int jo = 0; jo < 16; ++jo) {
        const float4 c2q = *(const float4*)(c2p + jo * 4);
        const float c2a[4] = {c2q.x, c2q.y, c2q.z, c2q.w};
#pragma unroll
        for (int ji = 0; ji < 4; ++ji) {
          const int j = jo * 4 + ji;
          const float4 c0 = *(const float4*)(cp + j * 8);
          const float4 c1 = *(const float4*)(cp + j * 8 + 4);
          float dot = 0.0f;
          dot = fmaf(en0, c0.x, dot); dot = fmaf(en1, c0.y, dot);
          dot = fmaf(en2, c0.z, dot); dot = fmaf(en3, c0.w, dot);
          dot = fmaf(en4, c1.x, dot); dot = fmaf(en5, c1.y, dot);
          dot = fmaf(en6, c1.z, dot); dot = fmaf(en7, c1.w, dot);
          const float dist = fmaf(-2.0f, dot, sv) + c2a[ji];
          if (dist < dmin) { dmin = dist; jmin = j; }  // strict <, j asc = first-min
        }
      }
      int kmin = (jmin << 4) + grp;
      // in-wave argmin over the wave's 4 grp-subsets (min-with-lowest-k tie is
      // associative; identical to sequential first-min scan — round-1 verified)
      float od = __shfl_xor(dmin, 16); int ok = __shfl_xor(kmin, 16);
      if (od < dmin || (od == dmin && ok < kmin)) { dmin = od; kmin = ok; }
      od = __shfl_xor(dmin, 32); ok = __shfl_xor(kmin, 32);
      if (od < dmin || (od == dmin && ok < kmin)) { dmin = od; kmin = ok; }
      if ((tid & 48) == 0) {
        s_cd[(tid >> 6) * 16 + col] = dmin;
        s_ck[(tid >> 6) * 16 + col] = kmin;
      }
    }
    __syncthreads();

    // ---- D: per-lane 4-way argmin (redundant, associative => identical),
    // codes from the 16 grp==0 lanes, STE in-register (16-way broadcast cb-row
    // load), out-proj (einsum SOP, FMA ascending d) + latent & residual update
    {
      float bd = s_cd[col]; int bk = s_ck[col];
#pragma unroll
      for (int w = 1; w < 4; ++w) {
        const float d2 = s_cd[w * 16 + col]; const int k2 = s_ck[w * 16 + col];
        if (d2 < bd || (d2 == bd && k2 < bk)) { bd = d2; bk = k2; }
      }
      if (grp == 0)
        out[((size_t)b * NCB + i) * TT + t0 + col] = (float)bk;

      const float* cr = cb + ((size_t)i * KK + bk) * 8;  // RAW codebook row
      const float4 cq0 = *(const float4*)(cr);
      const float4 cq1 = *(const float4*)(cr + 4);
      const float zqa[8] = {cq0.x, cq0.y, cq0.z, cq0.w, cq1.x, cq1.y, cq1.z, cq1.w};
      float qst[8];
#pragma unroll
      for (int d = 0; d < 8; ++d) {
        const float ze = s_ze[d * 16 + col];
        const float zq = zqa[d];
        qst[d] = ze + (zq - ze);                 // STE rounding mirrored
        if (grp == 0) {                          // loss counted once per (d,col)
          const float df = ze - zq;
          loss_acc = fmaf(df, df, loss_acc);     // loss precision uncritical (2% thr)
        }
      }
      const float* gw  = g_wout + ((size_t)i * 16 + grp) * 256;  // 32 j x 8
      const float* obp = g_obt  + ((size_t)i * 16 + grp) * 32;
#pragma unroll 2
      for (int jo = 0; jo < 8; ++jo) {
        const float4 obq = *(const float4*)(obp + jo * 4);
        const float oba[4] = {obq.x, obq.y, obq.z, obq.w};
#pragma unroll
        for (int ji = 0; ji < 4; ++ji) {
          const int j = jo * 4 + ji;
          const float4 w0 = *(const float4*)(gw + j * 8);
          const float4 w1 = *(const float4*)(gw + j * 8 + 4);
          float dot = 0.0f;
          dot = fmaf(w0.x, qst[0], dot); dot = fmaf(w0.y, qst[1], dot);
          dot = fmaf(w0.z, qst[2], dot); dot = fmaf(w0.w, qst[3], dot);
          dot = fmaf(w1.x, qst[4], dot); dot = fmaf(w1.y, qst[5], dot);
          dot = fmaf(w1.z, qst[6], dot); dot = fmaf(w1.w, qst[7], dot);
          const float lat = dot + oba[ji];       // einsum + bias (one rounded add)
          lr[j] += lat;                          // latent += lat_i (np per-step f32)
          s_res[col * SRES + grp + (j << 4)] -= lat;  // residual -= lat_i
        }
      }
    }
    // no trailing barrier: next stage touches only s_win (disjoint);
    // loop-top barrier orders D's s_res writes vs next A1 reads.
  }

  // latent output (exact per-step accumulation)
  {
    float* lat = out + OUT_LAT;
#pragma unroll
    for (int j = 0; j < 32; ++j) {
      const int c = grp + (j << 4);
      lat[((size_t)b * DIN + c) * TT + t0 + col] = lr[j];
    }
  }

  // loss reduce (nonzero only lanes 0..15 of wave 0), one atomic per block
  if (tid < 64) {
    float v = loss_acc;
#pragma unroll
    for (int off = 32; off; off >>= 1) v += __shfl_down(v, off);
    if (tid == 0) atomicAdd(&g_loss, (double)v);
  }
}

// ---------- epilogue: finalize scalar losses ----------
__global__ void rvq_epi_k(float* __restrict__ out) {
  const float m = (float)(g_loss / 524288.0);  // B*D_CB*T
  out[OUT_CLOSS]     = m;
  out[OUT_CLOSS + 1] = m;
}

extern "C" void kernel_launch(void* const* d_in, const int* in_sizes, int n_in,
                              void* d_out, int out_size, void* d_ws, size_t ws_size,
                              hipStream_t stream) {
  const float* z     = (const float*)d_in[0];
  const float* in_v  = (const float*)d_in[1];
  const float* in_g  = (const float*)d_in[2];
  const float* in_b  = (const float*)d_in[3];
  const float* out_v = (const float*)d_in[4];
  const float* out_g = (const float*)d_in[5];
  const float* out_b = (const float*)d_in[6];
  const float* cb    = (const float*)d_in[7];
  float* out = (float*)d_out;
  (void)d_ws; (void)ws_size;

  prep_win_k <<<2, 64, 0, stream>>>(in_v, in_g);
  prep_wout_k<<<18, 256, 0, stream>>>(out_v, out_g, out_b);
  prep_cbn_k <<<36, 256, 0, stream>>>(cb);
  rvq_main_k <<<4096, 256, 0, stream>>>(z, in_b, cb, out);
  rvq_epi_k  <<<1, 1, 0, stream>>>(out);
}